// Round 8
// baseline (1987.672 us; speedup 1.0000x reference)
//
#include <hip/hip_runtime.h>

// ---------------------------------------------------------------------------
// VQEmbeddingEMA forward on MI355X (gfx950), fp32.
//   N = 32*2048 = 65536 tokens, D = 64, K = 1024 codes.
// Round 8: assign back to TPT=1 (48-VGPR body of round 6) but 8-way K split
// -> 2048 blocks = 8 waves/SIMD (was 3.5) to hide SMEM latency.
// finalize2 fused into gather (block k owns dw row k).
// ---------------------------------------------------------------------------

#define N_TOK   65536
#define KCODES  1024

#define Q_OFF   0
#define SC_OFF  4194304
#define NE_OFF  4194307
#define NC_OFF  4259843
#define NW_OFF  4260867
#define NU_OFF  4326403

// ws layout (floats)
#define WS_COUNTS 0              // [1024]  (atomic, zeroed)
#define WS_LOSS   1024           // [1]     (atomic, zeroed)
#define WS_HN     1028           // [1024]
#define WS_IDX    2052           // [65536] int
#define WS_PS     67588          // [8][65536] partial scores
#define WS_PI     591876         // [8][65536] partial indices (int)

// 0.5 * |e_k|^2 per code
__global__ __launch_bounds__(256) void hn_kernel(const float* __restrict__ emb,
                                                 float* __restrict__ hn) {
    int k = blockIdx.x * 256 + threadIdx.x;   // grid 4x256 -> 1024
    const float4* e4 = reinterpret_cast<const float4*>(emb) + (size_t)k * 16;
    float4 a = make_float4(0.f, 0.f, 0.f, 0.f);
#pragma unroll
    for (int i = 0; i < 16; ++i) {
        float4 e = e4[i];
        a.x = fmaf(e.x, e.x, a.x);
        a.y = fmaf(e.y, e.y, a.y);
        a.z = fmaf(e.z, e.z, a.z);
        a.w = fmaf(e.w, e.w, a.w);
    }
    hn[k] = 0.5f * ((a.x + a.y) + (a.z + a.w));
}

// One token per thread, 128 codes per block (8-way K split), 8 waves/SIMD.
// e / hn accesses are wave-uniform -> scalar loads on the SMEM pipe.
__global__ __launch_bounds__(256, 8) void assign_kernel(
    const float* __restrict__ x, const float* __restrict__ emb,
    const float* __restrict__ hn, float* __restrict__ pscore,
    int* __restrict__ pidx) {
    const int part  = blockIdx.x & 7;      // 0..7
    const int group = blockIdx.x >> 3;     // 0..255
    const int tok   = group * 256 + threadIdx.x;
    const int kbase = part * 128;

    const float4* __restrict__ x4 =
        reinterpret_cast<const float4*>(x) + (size_t)tok * 16;
    float4 xr[16];
#pragma unroll
    for (int i = 0; i < 16; ++i) xr[i] = x4[i];

    const float4* __restrict__ e4 =
        reinterpret_cast<const float4*>(emb) + (size_t)kbase * 16;
    const float* __restrict__ hb = hn + kbase;

    float best = 3.0e38f;
    int bloc = 0;

    for (int kk = 0; kk < 128; kk += 2) {
        const float4* __restrict__ e0 = e4 + (size_t)kk * 16;
        float4 a = make_float4(0.f, 0.f, 0.f, 0.f);
        float4 b = make_float4(0.f, 0.f, 0.f, 0.f);
#pragma unroll
        for (int i = 0; i < 16; ++i) {
            float4 xv = xr[i];
            float4 ea = e0[i];        // uniform -> s_load
            float4 eb = e0[16 + i];   // uniform -> s_load
            a.x = fmaf(xv.x, ea.x, a.x);
            a.y = fmaf(xv.y, ea.y, a.y);
            a.z = fmaf(xv.z, ea.z, a.z);
            a.w = fmaf(xv.w, ea.w, a.w);
            b.x = fmaf(xv.x, eb.x, b.x);
            b.y = fmaf(xv.y, eb.y, b.y);
            b.z = fmaf(xv.z, eb.z, b.z);
            b.w = fmaf(xv.w, eb.w, b.w);
        }
        float d0 = (a.x + a.y) + (a.z + a.w);
        float d1 = (b.x + b.y) + (b.z + b.w);
        float s0 = hb[kk]     - d0;
        float s1 = hb[kk + 1] - d1;
        // ascending k + strict < == first-minimum tie-break (jnp.argmin)
        if (s0 < best) { best = s0; bloc = kk; }
        if (s1 < best) { best = s1; bloc = kk + 1; }
    }

    pscore[part * N_TOK + tok] = best;
    pidx  [part * N_TOK + tok] = kbase + bloc;
}

// Combine 8 partial candidates; write idx, quantized, loss, counts.
__global__ __launch_bounds__(256) void merge_kernel(
    const float* __restrict__ x, const float* __restrict__ emb,
    const float* __restrict__ pscore, const int* __restrict__ pidx,
    float* __restrict__ counts, int* __restrict__ idx,
    float* __restrict__ loss_sum, float* __restrict__ qout) {
    const int tok = blockIdx.x * 256 + threadIdx.x;

    float bs = pscore[tok];
    int   bi = pidx[tok];
#pragma unroll
    for (int h = 1; h < 8; ++h) {
        float s  = pscore[h * N_TOK + tok];
        int   i2 = pidx[h * N_TOK + tok];
        // later h always has larger idx, so strict < keeps lowest-idx min
        if (s < bs) { bs = s; bi = i2; }
    }
    idx[tok] = bi;

    const float4* x4  = reinterpret_cast<const float4*>(x) + (size_t)tok * 16;
    const float4* eb4 = reinterpret_cast<const float4*>(emb) + (size_t)bi * 16;
    float4* q4 = reinterpret_cast<float4*>(qout) + (size_t)tok * 16;

    float lsum = 0.0f;
#pragma unroll
    for (int i = 0; i < 16; ++i) {
        float4 xv = x4[i];
        float4 e  = eb4[i];
        q4[i] = e;
        float d0 = xv.x - e.x; lsum = fmaf(d0, d0, lsum);
        float d1 = xv.y - e.y; lsum = fmaf(d1, d1, lsum);
        float d2 = xv.z - e.z; lsum = fmaf(d2, d2, lsum);
        float d3 = xv.w - e.w; lsum = fmaf(d3, d3, lsum);
    }

    atomicAdd(&counts[bi], 1.0f);

#pragma unroll
    for (int off = 32; off; off >>= 1) lsum += __shfl_down(lsum, off, 64);
    if ((threadIdx.x & 63) == 0) atomicAdd(loss_sum, lsum);
}

// counts-based outputs: new_count, new_usage, scalars (one block, k = tid).
// Runs BEFORE gather (gather reads out[NC_OFF+k]).
__global__ __launch_bounds__(1024) void finalize1(
    const float* __restrict__ counts, const float* __restrict__ loss_sum,
    const float* __restrict__ ema_count, const float* __restrict__ usage,
    float* __restrict__ out) {
    const int k = threadIdx.x;
    const float cnt = counts[k];
    const float raw = 0.999f * ema_count[k] + 0.001f * cnt;
    const float p = cnt * (1.0f / 65536.0f);
    const float term = p * logf(p + 1e-10f);

    float v1 = raw, v2 = term;
#pragma unroll
    for (int off = 32; off; off >>= 1) {
        v1 += __shfl_down(v1, off, 64);
        v2 += __shfl_down(v2, off, 64);
    }
    __shared__ float r1[16], r2[16];
    __shared__ float s_n, s_plog;
    if ((k & 63) == 0) { r1[k >> 6] = v1; r2[k >> 6] = v2; }
    __syncthreads();
    if (k < 64) {
        float a = (k < 16) ? r1[k] : 0.0f;
        float b = (k < 16) ? r2[k] : 0.0f;
#pragma unroll
        for (int off = 8; off; off >>= 1) {
            a += __shfl_down(a, off, 64);
            b += __shfl_down(b, off, 64);
        }
        if (k == 0) { s_n = a; s_plog = b; }
    }
    __syncthreads();

    const float n = s_n;
    const float smoothed = (raw + 1e-5f) / (n + 1024.0f * 1e-5f) * n;
    out[NC_OFF + k] = smoothed;
    out[NU_OFF + k] = (usage[k] + (cnt > 0.0f ? 1.0f : 0.0f)) * 0.5f;
    if (k == 0) {
        const float lm = loss_sum[0] * (1.0f / 4194304.0f);
        out[SC_OFF + 0] = 0.25f * lm;    // commitment_loss
        out[SC_OFF + 1] = lm;            // codebook_loss
        out[SC_OFF + 2] = expf(-s_plog); // perplexity
    }
}

// Segment-sum via scan-gather + fused EMA epilogue: block k sums x rows of
// tokens with idx==k (ascending-token order == jax.ops.segment_sum), then
// wave 0 applies the EMA and writes new_weight / new_embedding directly.
__global__ __launch_bounds__(512) void gather_kernel(
    const float* __restrict__ x, const int* __restrict__ idx,
    const float* __restrict__ ema_weight, const float* __restrict__ out_nc,
    float* __restrict__ new_weight, float* __restrict__ new_embedding) {
    const int k    = blockIdx.x;          // code
    const int wave = threadIdx.x >> 6;    // 0..7
    const int lane = threadIdx.x & 63;    // dimension

    float acc = 0.0f;
    const int begin = wave * (N_TOK / 8);
    const int end   = begin + (N_TOK / 8);
    for (int base = begin; base < end; base += 128) {
        int mi0 = idx[base + lane];
        int mi1 = idx[base + 64 + lane];
        unsigned long long m0 = __ballot(mi0 == k);
        unsigned long long m1 = __ballot(mi1 == k);
        while (m0) {
            int b = __ffsll((long long)m0) - 1;
            m0 &= m0 - 1;
            acc += x[(size_t)(base + b) * 64 + lane];
        }
        while (m1) {
            int b = __ffsll((long long)m1) - 1;
            m1 &= m1 - 1;
            acc += x[(size_t)(base + 64 + b) * 64 + lane];
        }
    }

    __shared__ float red[8][64];
    red[wave][lane] = acc;
    __syncthreads();
    if (wave == 0) {
        float s = red[0][lane];
#pragma unroll
        for (int w = 1; w < 8; ++w) s += red[w][lane];
        const float nc = out_nc[k];                 // uniform scalar load
        float w = 0.999f * ema_weight[(size_t)k * 64 + lane] + 0.001f * s;
        new_weight[(size_t)k * 64 + lane] = w;
        new_embedding[(size_t)k * 64 + lane] = w / nc;
    }
}

extern "C" void kernel_launch(void* const* d_in, const int* in_sizes, int n_in,
                              void* d_out, int out_size, void* d_ws, size_t ws_size,
                              hipStream_t stream) {
    const float* x          = (const float*)d_in[0];
    const float* emb        = (const float*)d_in[1];
    const float* ema_count  = (const float*)d_in[2];
    const float* ema_weight = (const float*)d_in[3];
    const float* usage      = (const float*)d_in[4];
    float* out = (float*)d_out;
    float* ws  = (float*)d_ws;

    float* counts = ws + WS_COUNTS;
    float* loss   = ws + WS_LOSS;
    float* hn     = ws + WS_HN;
    int*   idx    = (int*)(ws + WS_IDX);
    float* ps     = ws + WS_PS;
    int*   pi     = (int*)(ws + WS_PI);

    // ws is re-poisoned to 0xAA before every timed launch -> zero the
    // atomic regions (counts + loss). Everything else is fully written.
    hipMemsetAsync(ws, 0, 1025 * sizeof(float), stream);

    hn_kernel<<<4, 256, 0, stream>>>(emb, hn);
    assign_kernel<<<2048, 256, 0, stream>>>(x, emb, hn, ps, pi);
    merge_kernel<<<256, 256, 0, stream>>>(x, emb, ps, pi, counts, idx, loss,
                                          out + Q_OFF);
    finalize1<<<1, 1024, 0, stream>>>(counts, loss, ema_count, usage, out);
    gather_kernel<<<1024, 512, 0, stream>>>(x, idx, ema_weight, out + NC_OFF,
                                            out + NW_OFF, out + NE_OFF);
}

// Round 9
// 319.376 us; speedup vs baseline: 6.2236x; 6.2236x over previous
//
#include <hip/hip_runtime.h>

// ---------------------------------------------------------------------------
// VQEmbeddingEMA forward on MI355X (gfx950), fp32.
//   N = 32*2048 = 65536 tokens, D = 64, K = 1024 codes.
// Round 9: flipped residency. Lane l holds code e-row in VGPRs (loaded once);
// x streams through the scalar pipe (wave-uniform sequential -> deep SGPR
// prefetch, K$-shared across the block's 4 waves). Per token: 64 v_fmac with
// scalar x operand + 6-step shfl_xor min-reduce + ballot pick (tie -> lowest
// lane == lowest code == jnp.argmin). launch_bounds(256,5): cap 102 VGPR,
// e[64] cannot spill (round-8 lesson: cap 64 forced a 6.3 GB scratch spill).
// ---------------------------------------------------------------------------

#define N_TOK   65536
#define KCODES  1024

#define Q_OFF   0
#define SC_OFF  4194304
#define NE_OFF  4194307
#define NC_OFF  4259843
#define NW_OFF  4260867
#define NU_OFF  4326403

// ws layout (floats)
#define WS_COUNTS 0              // [1024]  (atomic, zeroed)
#define WS_LOSS   1024           // [1]     (atomic, zeroed)
#define WS_IDX    1028           // [65536] int
#define WS_PS     66564          // [4][65536] partial scores
#define WS_PI     328708         // [4][65536] partial indices (int)

// Lane l of wave w owns code part*256 + w*64 + l. e resident in VGPRs.
// Each wave scans 128 tokens; block combines its 4 waves' candidates in LDS.
__global__ __launch_bounds__(256, 5) void assign_kernel(
    const float* __restrict__ x, const float* __restrict__ emb,
    float* __restrict__ pscore, int* __restrict__ pidx) {
    const int part = blockIdx.x & 3;       // 0..3   (256 codes per part)
    const int grp  = blockIdx.x >> 2;      // 0..511 (128 tokens per group)
    const int wid  = threadIdx.x >> 6;     // 0..3
    const int lane = threadIdx.x & 63;
    const int code = part * 256 + wid * 64 + lane;

    // e row for this lane's code -> VGPRs, loaded once; hn = 0.5*|e|^2.
    const float4* __restrict__ e4 =
        reinterpret_cast<const float4*>(emb) + (size_t)code * 16;
    float er[64];
#pragma unroll
    for (int i = 0; i < 16; ++i) {
        float4 v = e4[i];
        er[4 * i + 0] = v.x; er[4 * i + 1] = v.y;
        er[4 * i + 2] = v.z; er[4 * i + 3] = v.w;
    }
    float hn = 0.0f;
#pragma unroll
    for (int i = 0; i < 64; ++i) hn = fmaf(er[i], er[i], hn);
    hn *= 0.5f;

    __shared__ float cs[4][128];
    __shared__ int   ci[4][128];

    const int tok0 = grp * 128;
    for (int t = 0; t < 128; ++t) {
        const float* __restrict__ xs = x + (size_t)(tok0 + t) * 64; // uniform
        float a0 = 0.0f, a1 = 0.0f;
#pragma unroll
        for (int i = 0; i < 64; i += 2) {
            a0 = fmaf(xs[i],     er[i],     a0);   // v_fmac v, s, v
            a1 = fmaf(xs[i + 1], er[i + 1], a1);
        }
        float s = hn - (a0 + a1);     // argmin_k 0.5|e|^2 - x.e

        // 64-lane min-reduce, then pick lowest lane among equals
        float m = s;
#pragma unroll
        for (int off = 32; off; off >>= 1) m = fminf(m, __shfl_xor(m, off, 64));
        unsigned long long bal = __ballot(s == m);
        int first = __ffsll((long long)bal) - 1;
        if (lane == first) { cs[wid][t] = s; ci[wid][t] = code; }
    }
    __syncthreads();

    if (threadIdx.x < 128) {
        const int t = threadIdx.x;
        float bs = cs[0][t];
        int   bi = ci[0][t];
#pragma unroll
        for (int w = 1; w < 4; ++w) {
            float s2 = cs[w][t];
            int   i2 = ci[w][t];
            if (s2 < bs) { bs = s2; bi = i2; }  // ascending w = ascending code
        }
        pscore[part * N_TOK + tok0 + t] = bs;
        pidx  [part * N_TOK + tok0 + t] = bi;
    }
}

// Combine 4 partial candidates; write idx, quantized, loss, counts.
__global__ __launch_bounds__(256) void merge_kernel(
    const float* __restrict__ x, const float* __restrict__ emb,
    const float* __restrict__ pscore, const int* __restrict__ pidx,
    float* __restrict__ counts, int* __restrict__ idx,
    float* __restrict__ loss_sum, float* __restrict__ qout) {
    const int tok = blockIdx.x * 256 + threadIdx.x;

    float bs = pscore[tok];
    int   bi = pidx[tok];
#pragma unroll
    for (int h = 1; h < 4; ++h) {
        float s  = pscore[h * N_TOK + tok];
        int   i2 = pidx[h * N_TOK + tok];
        // later h always has larger idx, so strict < keeps lowest-idx min
        if (s < bs) { bs = s; bi = i2; }
    }
    idx[tok] = bi;

    const float4* x4  = reinterpret_cast<const float4*>(x) + (size_t)tok * 16;
    const float4* eb4 = reinterpret_cast<const float4*>(emb) + (size_t)bi * 16;
    float4* q4 = reinterpret_cast<float4*>(qout) + (size_t)tok * 16;

    float lsum = 0.0f;
#pragma unroll
    for (int i = 0; i < 16; ++i) {
        float4 xv = x4[i];
        float4 e  = eb4[i];
        q4[i] = e;
        float d0 = xv.x - e.x; lsum = fmaf(d0, d0, lsum);
        float d1 = xv.y - e.y; lsum = fmaf(d1, d1, lsum);
        float d2 = xv.z - e.z; lsum = fmaf(d2, d2, lsum);
        float d3 = xv.w - e.w; lsum = fmaf(d3, d3, lsum);
    }

    atomicAdd(&counts[bi], 1.0f);

#pragma unroll
    for (int off = 32; off; off >>= 1) lsum += __shfl_down(lsum, off, 64);
    if ((threadIdx.x & 63) == 0) atomicAdd(loss_sum, lsum);
}

// counts-based outputs: new_count, new_usage, scalars (one block, k = tid).
// Runs BEFORE gather (gather reads out[NC_OFF+k]).
__global__ __launch_bounds__(1024) void finalize1(
    const float* __restrict__ counts, const float* __restrict__ loss_sum,
    const float* __restrict__ ema_count, const float* __restrict__ usage,
    float* __restrict__ out) {
    const int k = threadIdx.x;
    const float cnt = counts[k];
    const float raw = 0.999f * ema_count[k] + 0.001f * cnt;
    const float p = cnt * (1.0f / 65536.0f);
    const float term = p * logf(p + 1e-10f);

    float v1 = raw, v2 = term;
#pragma unroll
    for (int off = 32; off; off >>= 1) {
        v1 += __shfl_down(v1, off, 64);
        v2 += __shfl_down(v2, off, 64);
    }
    __shared__ float r1[16], r2[16];
    __shared__ float s_n, s_plog;
    if ((k & 63) == 0) { r1[k >> 6] = v1; r2[k >> 6] = v2; }
    __syncthreads();
    if (k < 64) {
        float a = (k < 16) ? r1[k] : 0.0f;
        float b = (k < 16) ? r2[k] : 0.0f;
#pragma unroll
        for (int off = 8; off; off >>= 1) {
            a += __shfl_down(a, off, 64);
            b += __shfl_down(b, off, 64);
        }
        if (k == 0) { s_n = a; s_plog = b; }
    }
    __syncthreads();

    const float n = s_n;
    const float smoothed = (raw + 1e-5f) / (n + 1024.0f * 1e-5f) * n;
    out[NC_OFF + k] = smoothed;
    out[NU_OFF + k] = (usage[k] + (cnt > 0.0f ? 1.0f : 0.0f)) * 0.5f;
    if (k == 0) {
        const float lm = loss_sum[0] * (1.0f / 4194304.0f);
        out[SC_OFF + 0] = 0.25f * lm;    // commitment_loss
        out[SC_OFF + 1] = lm;            // codebook_loss
        out[SC_OFF + 2] = expf(-s_plog); // perplexity
    }
}

// Segment-sum via scan-gather + fused EMA epilogue: block k sums x rows of
// tokens with idx==k (ascending-token order == jax.ops.segment_sum), then
// wave 0 applies the EMA and writes new_weight / new_embedding directly.
__global__ __launch_bounds__(512) void gather_kernel(
    const float* __restrict__ x, const int* __restrict__ idx,
    const float* __restrict__ ema_weight, const float* __restrict__ out_nc,
    float* __restrict__ new_weight, float* __restrict__ new_embedding) {
    const int k    = blockIdx.x;          // code
    const int wave = threadIdx.x >> 6;    // 0..7
    const int lane = threadIdx.x & 63;    // dimension

    float acc = 0.0f;
    const int begin = wave * (N_TOK / 8);
    const int end   = begin + (N_TOK / 8);
    for (int base = begin; base < end; base += 128) {
        int mi0 = idx[base + lane];
        int mi1 = idx[base + 64 + lane];
        unsigned long long m0 = __ballot(mi0 == k);
        unsigned long long m1 = __ballot(mi1 == k);
        while (m0) {
            int b = __ffsll((long long)m0) - 1;
            m0 &= m0 - 1;
            acc += x[(size_t)(base + b) * 64 + lane];
        }
        while (m1) {
            int b = __ffsll((long long)m1) - 1;
            m1 &= m1 - 1;
            acc += x[(size_t)(base + 64 + b) * 64 + lane];
        }
    }

    __shared__ float red[8][64];
    red[wave][lane] = acc;
    __syncthreads();
    if (wave == 0) {
        float s = red[0][lane];
#pragma unroll
        for (int w = 1; w < 8; ++w) s += red[w][lane];
        const float nc = out_nc[k];                 // uniform scalar load
        float w = 0.999f * ema_weight[(size_t)k * 64 + lane] + 0.001f * s;
        new_weight[(size_t)k * 64 + lane] = w;
        new_embedding[(size_t)k * 64 + lane] = w / nc;
    }
}

extern "C" void kernel_launch(void* const* d_in, const int* in_sizes, int n_in,
                              void* d_out, int out_size, void* d_ws, size_t ws_size,
                              hipStream_t stream) {
    const float* x          = (const float*)d_in[0];
    const float* emb        = (const float*)d_in[1];
    const float* ema_count  = (const float*)d_in[2];
    const float* ema_weight = (const float*)d_in[3];
    const float* usage      = (const float*)d_in[4];
    float* out = (float*)d_out;
    float* ws  = (float*)d_ws;

    float* counts = ws + WS_COUNTS;
    float* loss   = ws + WS_LOSS;
    int*   idx    = (int*)(ws + WS_IDX);
    float* ps     = ws + WS_PS;
    int*   pi     = (int*)(ws + WS_PI);

    // ws is re-poisoned to 0xAA before every timed launch -> zero the
    // atomic regions (counts + loss). Everything else is fully written.
    hipMemsetAsync(ws, 0, 1025 * sizeof(float), stream);

    assign_kernel<<<2048, 256, 0, stream>>>(x, emb, ps, pi);
    merge_kernel<<<256, 256, 0, stream>>>(x, emb, ps, pi, counts, idx, loss,
                                          out + Q_OFF);
    finalize1<<<1, 1024, 0, stream>>>(counts, loss, ema_count, usage, out);
    gather_kernel<<<1024, 512, 0, stream>>>(x, idx, ema_weight, out + NC_OFF,
                                            out + NW_OFF, out + NE_OFF);
}